// Round 1
// baseline (26.115 us; speedup 1.0000x reference)
//
#include <hip/hip_runtime.h>

#define HW 56
#define CH 64          // channels after pair-sum
#define CI 32          // output channels
#define PLANE (HW*HW)  // 3136

__global__ __launch_bounds__(256) void convshift_kernel(
    const float* __restrict__ x, const float* __restrict__ Wt, float* __restrict__ out)
{
    int idx = blockIdx.x * blockDim.x + threadIdx.x;
    if (idx >= CI * PLANE) return;
    int i   = idx / PLANE;
    int rem = idx - i * PLANE;
    int h   = rem / HW;
    int w   = rem - h * HW;

    const float* __restrict__ Wr = Wt + i * (CH * 3);
    const float* __restrict__ xa = x + w;               // + c*PLANE + hh*HW
    const float* __restrict__ xb = x + 64 * PLANE + w;

    const bool k0v = (h > 0);
    const bool k2v = (h < HW - 1);

    float acc = 0.f;

    #pragma unroll 8
    for (int c = 0; c < CH; ++c) {
        int base = c * PLANE + h * HW;
        float w0 = Wr[c * 3 + 0];
        float w1 = Wr[c * 3 + 1];
        float w2 = Wr[c * 3 + 2];
        // center tap (always valid)
        float t1 = xa[base] + xb[base];
        acc += t1 * w1;
        // upper tap (h-1)
        if (k0v) {
            float t0 = xa[base - HW] + xb[base - HW];
            acc += t0 * w0;
        }
        // lower tap (h+1)
        if (k2v) {
            float t2 = xa[base + HW] + xb[base + HW];
            acc += t2 * w2;
        }
    }

    // fuse jnp.roll(out, +1, axis=3): value computed at w is stored at (w+1) % 56
    int wst = w + 1; if (wst == HW) wst = 0;
    out[i * PLANE + h * HW + wst] = acc;
}

extern "C" void kernel_launch(void* const* d_in, const int* in_sizes, int n_in,
                              void* d_out, int out_size, void* d_ws, size_t ws_size,
                              hipStream_t stream) {
    const float* x  = (const float*)d_in[0];   // (1,128,56,56) f32
    const float* Wt = (const float*)d_in[1];   // (32,64,3) f32
    float* out = (float*)d_out;                // (1,32,56,56) f32

    const int total = CI * PLANE;              // 100352 = 392 * 256
    dim3 grid(total / 256), block(256);
    hipLaunchKernelGGL(convshift_kernel, grid, block, 0, stream, x, Wt, out);
}

// Round 2
// 14.358 us; speedup vs baseline: 1.8189x; 1.8189x over previous
//
#include <hip/hip_runtime.h>

#define HW 56
#define PLANE 3136     // 56*56
#define CH 64          // channels after pair-sum
#define CI 32          // output channels

// grid = (13 pixel-chunks, 32 output channels), block = 256
// 13*256 = 3328 >= 3136 (last chunk partially active)
__global__ __launch_bounds__(256) void convshift_kernel(
    const float* __restrict__ x, const float* __restrict__ Wt, float* __restrict__ out)
{
    __shared__ float sW[CH * 3];
    const int i   = blockIdx.y;
    const int tid = threadIdx.x;
    if (tid < CH * 3) sW[tid] = Wt[i * (CH * 3) + tid];
    __syncthreads();

    const int p  = blockIdx.x * 256 + tid;
    const int pc = (p < PLANE) ? p : (PLANE - 1);   // clamp inactive threads to a safe addr
    const int h  = pc / HW;
    const int w  = pc - h * HW;

    const int hm = (h > 0)      ? h - 1 : 0;        // clamped; contribution masked at end
    const int hp = (h < HW - 1) ? h + 1 : HW - 1;
    const bool v0 = (h > 0), v2 = (h < HW - 1);

    const float* __restrict__ xa = x + w;                // first 64 channels
    const float* __restrict__ xb = x + CH * PLANE + w;   // second 64 channels
    const int r0 = hm * HW, r1 = h * HW, r2 = hp * HW;

    // 6 independent accumulator chains (tap x half)
    float ca0 = 0.f, ca1 = 0.f, ca2 = 0.f;
    float cb0 = 0.f, cb1 = 0.f, cb2 = 0.f;

    // double-buffered register staging: 8 channels x 6 values in flight
    float A0[2][8], A1[2][8], A2[2][8], B0[2][8], B1[2][8], B2[2][8];

    // prefetch chunk 0
    #pragma unroll
    for (int j = 0; j < 8; ++j) {
        const int o = j * PLANE;
        A0[0][j] = xa[o + r0]; A1[0][j] = xa[o + r1]; A2[0][j] = xa[o + r2];
        B0[0][j] = xb[o + r0]; B1[0][j] = xb[o + r1]; B2[0][j] = xb[o + r2];
    }

    #pragma unroll
    for (int ch = 0; ch < 8; ++ch) {
        const int cur = ch & 1, nxt = cur ^ 1;
        if (ch < 7) {
            const int cb = (ch + 1) * 8;
            #pragma unroll
            for (int j = 0; j < 8; ++j) {
                const int o = (cb + j) * PLANE;
                A0[nxt][j] = xa[o + r0]; A1[nxt][j] = xa[o + r1]; A2[nxt][j] = xa[o + r2];
                B0[nxt][j] = xb[o + r0]; B1[nxt][j] = xb[o + r1]; B2[nxt][j] = xb[o + r2];
            }
        }
        const int cb = ch * 8;
        #pragma unroll
        for (int j = 0; j < 8; ++j) {
            const int c = cb + j;
            const float w0 = sW[c * 3 + 0];
            const float w1 = sW[c * 3 + 1];
            const float w2 = sW[c * 3 + 2];
            ca0 += A0[cur][j] * w0;  cb0 += B0[cur][j] * w0;
            ca1 += A1[cur][j] * w1;  cb1 += B1[cur][j] * w1;
            ca2 += A2[cur][j] * w2;  cb2 += B2[cur][j] * w2;
        }
    }

    float acc = (ca1 + cb1);
    if (v0) acc += (ca0 + cb0);      // mask clamped top row once, not per-channel
    if (v2) acc += (ca2 + cb2);      // mask clamped bottom row once

    if (p < PLANE) {
        // fuse jnp.roll(out, +1, axis=3)
        int wst = w + 1; if (wst == HW) wst = 0;
        out[i * PLANE + h * HW + wst] = acc;
    }
}

extern "C" void kernel_launch(void* const* d_in, const int* in_sizes, int n_in,
                              void* d_out, int out_size, void* d_ws, size_t ws_size,
                              hipStream_t stream) {
    const float* x  = (const float*)d_in[0];   // (1,128,56,56) f32
    const float* Wt = (const float*)d_in[1];   // (32,64,3) f32
    float* out = (float*)d_out;                // (1,32,56,56) f32

    dim3 grid(13, CI), block(256);
    hipLaunchKernelGGL(convshift_kernel, grid, block, 0, stream, x, Wt, out);
}